// Round 1
// 678.929 us; speedup vs baseline: 1.0693x; 1.0693x over previous
//
#include <hip/hip_runtime.h>
#include <cstdint>
#include <cstddef>

// Problem: trajectory[b,t,k] = sum_d x0[b,d] * expm(t*dt*A)[k,d]
//   B=4096, T=100, D=256, dt=0.05, t = 0..99
// Strategy:
//   Phase 1 (fp32): M = expm(dt*A) by order-5 Taylor (Horner, 4 matmuls);
//                   E[t] = M^t by doubling levels E[2^j + r] = E[2^j]*E[r].
//                   mm256 dual-writes fp32 E and fp16 Wh (f2h fused).
//   Phase 2 (fp16 MFMA): C[4096 x 25600] = X0 * W^T, W[t*256+k][d] = E[t][k][d].
//                   m97 structure: global_load_lds width16 + XOR chunk swizzle.

#define TSTEPS 100
#define NCOLS  (TSTEPS * 256)   // 25600
#define DT     0.05f

typedef _Float16 half8 __attribute__((ext_vector_type(8)));
typedef _Float16 half4 __attribute__((ext_vector_type(4)));
typedef float    f32x4 __attribute__((ext_vector_type(4)));

// async global->LDS, 16B per lane; LDS dest is wave-uniform base + lane*16
__device__ __forceinline__ void gload16(const _Float16* g, _Float16* l) {
  __builtin_amdgcn_global_load_lds(
      (const __attribute__((address_space(1))) void*)g,
      (__attribute__((address_space(3))) void*)l, 16, 0, 0);
}

// ---------- init: R = I + c*A (Horner seed), Wh[0] = I (fp16) ----------
__global__ void init_kernel(const float* __restrict__ A, float* __restrict__ R,
                            _Float16* __restrict__ Wh0, float c) {
  int i = blockIdx.x * 256 + threadIdx.x;   // 65536 elements
  float id = ((i >> 8) == (i & 255)) ? 1.f : 0.f;
  R[i]  = id + c * A[i];
  Wh0[i] = (_Float16)id;
}

// ---------- batched 256x256 fp32 matmul: C_i = alpha*(A*B_i) (+ I) ----------
// grid: (16, cnt); 64x64 tile per block, 256 threads, 4x4 outputs/thread.
// A staged TRANSPOSED in LDS so inner loop is 2x ds_read_b128 + 16 FMA.
// Optionally dual-writes fp16 copy (f2h fused into epilogue).
__global__ __launch_bounds__(256) void mm256(const float* __restrict__ A,
                                             const float* __restrict__ Bb,
                                             float* __restrict__ Cb,
                                             _Float16* __restrict__ Hb,
                                             float alpha, int addI) {
  const float* B = Bb + (size_t)blockIdx.y * 65536;
  float*       C = Cb + (size_t)blockIdx.y * 65536;
  const int tm = (blockIdx.x & 3) * 64;
  const int tn = (blockIdx.x >> 2) * 64;
  __shared__ float Ats[32][68];   // [k][m] transposed; stride 68 f = 272 B (16B-aligned)
  __shared__ float Bs[32][68];    // [k][n]
  const int t  = threadIdx.x;
  const int tr = t >> 4, tc = t & 15;
  const int am = t >> 3, ak = (t & 7) * 4;    // A tile 64(m) x 32(k)
  const int bk = t >> 4, bn = (t & 15) * 4;   // B tile 32(k) x 64(n)
  float acc[4][4] = {};
  for (int kk = 0; kk < 256; kk += 32) {
    __syncthreads();
#pragma unroll
    for (int p = 0; p < 2; ++p) {
      const int m = am + p * 32;
      const float4 v = *(const float4*)(A + (size_t)(tm + m) * 256 + kk + ak);
      Ats[ak + 0][m] = v.x; Ats[ak + 1][m] = v.y;
      Ats[ak + 2][m] = v.z; Ats[ak + 3][m] = v.w;
    }
#pragma unroll
    for (int p = 0; p < 2; ++p) {
      const int k = bk + p * 16;
      *(float4*)(&Bs[k][bn]) = *(const float4*)(B + (size_t)(kk + k) * 256 + tn + bn);
    }
    __syncthreads();
#pragma unroll
    for (int k2 = 0; k2 < 32; ++k2) {
      const float4 a = *(const float4*)(&Ats[k2][tr * 4]);
      const float4 b = *(const float4*)(&Bs[k2][tc * 4]);
      acc[0][0] += a.x * b.x; acc[0][1] += a.x * b.y; acc[0][2] += a.x * b.z; acc[0][3] += a.x * b.w;
      acc[1][0] += a.y * b.x; acc[1][1] += a.y * b.y; acc[1][2] += a.y * b.z; acc[1][3] += a.y * b.w;
      acc[2][0] += a.z * b.x; acc[2][1] += a.z * b.y; acc[2][2] += a.z * b.z; acc[2][3] += a.z * b.w;
      acc[3][0] += a.w * b.x; acc[3][1] += a.w * b.y; acc[3][2] += a.w * b.z; acc[3][3] += a.w * b.w;
    }
  }
  const int n0c = tn + tc * 4;
#pragma unroll
  for (int i = 0; i < 4; ++i) {
    const int m = tm + tr * 4 + i;
    float4 v;
    v.x = alpha * acc[i][0]; v.y = alpha * acc[i][1];
    v.z = alpha * acc[i][2]; v.w = alpha * acc[i][3];
    if (addI) {
      const int d = m - n0c;
      if (d == 0) v.x += 1.f; else if (d == 1) v.y += 1.f;
      else if (d == 2) v.z += 1.f; else if (d == 3) v.w += 1.f;
    }
    *(float4*)(&C[(size_t)m * 256 + n0c]) = v;
    if (Hb) {
      _Float16* H = Hb + (size_t)blockIdx.y * 65536;
      half4 h;
      h[0] = (_Float16)v.x; h[1] = (_Float16)v.y;
      h[2] = (_Float16)v.z; h[3] = (_Float16)v.w;
      *(half4*)(&H[(size_t)m * 256 + n0c]) = h;
    }
  }
}

// ---------- fp32 -> fp16 convert, 4 elems/thread (X0 only) ----------
__global__ void f2h(const float* __restrict__ s, _Float16* __restrict__ d) {
  int i = (blockIdx.x * 256 + threadIdx.x) * 4;
  const float4 v = *(const float4*)(s + i);
  half4 h;
  h[0] = (_Float16)v.x; h[1] = (_Float16)v.y; h[2] = (_Float16)v.z; h[3] = (_Float16)v.w;
  *(half4*)(d + i) = h;
}

// ---------- phase 2: C[4096 x 25600] = X (4096x256) * W^T (25600x256), fp16 MFMA ----------
// 128x128 tile / block, 4 waves, each wave 64x64 (4x4 frags of 16x16x32).
// m97 structure: global_load_lds(16B) into LINEAR LDS [128][64] halves.
// Bank-conflict fix (rule #21, both-sides-or-neither): 16B-chunk XOR swizzle
//   LDS[row][chunk] holds global chunk (chunk ^ (row&7)); applied by
//   inverse-swizzling the per-lane GLOBAL source address (LDS write stays linear)
//   and XOR-ing the chunk index on the ds_read_b128 fragment reads.
__global__ __launch_bounds__(256) void gemm_out(const _Float16* __restrict__ X,
                                                const _Float16* __restrict__ W,
                                                float* __restrict__ out) {
  // XCD-chunked bijective swizzle: 6400 blocks % 8 == 0 -> 800 contiguous per XCD.
  const int nb = (blockIdx.x & 7) * 800 + (blockIdx.x >> 3);
  const int bt = nb & 31;   // M-tile (32) fastest: consecutive blocks share W tile
  const int nt = nb >> 5;   // N-tile (200)
  const int m0 = bt * 128, n0 = nt * 128;
  __shared__ __attribute__((aligned(16))) _Float16 As[128 * 64];  // 16 KB, linear
  __shared__ __attribute__((aligned(16))) _Float16 Bs[128 * 64];
  const int t    = threadIdx.x;
  const int lane = t & 63, wave = t >> 6;
  const int wm = (wave & 1) * 64, wn = (wave >> 1) * 64;
  const int quad = lane >> 4, l16 = lane & 15;
  // staging: per wave-call 1024 B = 8 rows; lane -> row rb+(lane>>3), chunk lane&7
  const int srow = lane >> 3;                    // row within 8-row group == row&7
  const int gcol = (((lane & 7) ^ srow) << 3);   // inverse-swizzled source col (halves)

  f32x4 acc[4][4];
#pragma unroll
  for (int i = 0; i < 4; ++i)
#pragma unroll
    for (int j = 0; j < 4; ++j) acc[i][j] = f32x4{0.f, 0.f, 0.f, 0.f};

  for (int kk = 0; kk < 256; kk += 64) {
    __syncthreads();
#pragma unroll
    for (int p = 0; p < 4; ++p) {
      const int rb = wave * 32 + p * 8;          // wave-uniform LDS row base
      const int r  = rb + srow;
      gload16(X + (size_t)(m0 + r) * 256 + kk + gcol, &As[rb * 64]);
      gload16(W + (size_t)(n0 + r) * 256 + kk + gcol, &Bs[rb * 64]);
    }
    __syncthreads();   // drains vmcnt(0): gload_lds complete
#pragma unroll
    for (int ks = 0; ks < 64; ks += 32) {
      half8 af[4], bf[4];
      const int ch = ((ks >> 3) + quad) ^ (l16 & 7);  // swizzled 16B-chunk index
#pragma unroll
      for (int i = 0; i < 4; ++i)
        af[i] = *(const half8*)(&As[(wm + i * 16 + l16) * 64 + (ch << 3)]);
#pragma unroll
      for (int j = 0; j < 4; ++j)
        bf[j] = *(const half8*)(&Bs[(wn + j * 16 + l16) * 64 + (ch << 3)]);
#pragma unroll
      for (int i = 0; i < 4; ++i)
#pragma unroll
        for (int j = 0; j < 4; ++j)
          acc[i][j] = __builtin_amdgcn_mfma_f32_16x16x32_f16(af[i], bf[j], acc[i][j], 0, 0, 0);
    }
  }
  // D layout (m89-verified): col = lane&15, row = quad*4 + reg
#pragma unroll
  for (int i = 0; i < 4; ++i)
#pragma unroll
    for (int j = 0; j < 4; ++j) {
      const int col = n0 + wn + j * 16 + l16;
#pragma unroll
      for (int r = 0; r < 4; ++r) {
        const int row = m0 + wm + i * 16 + quad * 4 + r;
        out[(size_t)row * NCOLS + col] = acc[i][j][r];
      }
    }
}

extern "C" void kernel_launch(void* const* d_in, const int* in_sizes, int n_in,
                              void* d_out, int out_size, void* d_ws, size_t ws_size,
                              hipStream_t stream) {
  const float* X0 = (const float*)d_in[0];   // [4096, 256]
  const float* A  = (const float*)d_in[1];   // [256, 256]
  float* out = (float*)d_out;                // [4096, 100, 256]

  // workspace layout (~41 MB total)
  float* E  = (float*)d_ws;                  // 100 * 65536 fp32 = 26.2 MB; E[t] row-major [k][d]
  float* R0 = E + (size_t)TSTEPS * 65536;    // Horner ping
  float* R1 = R0 + 65536;                    // Horner pong
  _Float16* Xh = (_Float16*)(R1 + 65536);    // 4096*256 fp16 = 2 MB
  _Float16* Wh = Xh + (size_t)4096 * 256;    // 25600*256 fp16 = 13.1 MB

  // ---- Phase 1: Wh[0] = I, E[1] = expm(dt*A) (order-5 Taylor, Horner) ----
  init_kernel<<<256, 256, 0, stream>>>(A, R0, Wh, DT / 5.f);
  mm256<<<dim3(16, 1), 256, 0, stream>>>(A, R0, R1, nullptr, DT / 4.f, 1);
  mm256<<<dim3(16, 1), 256, 0, stream>>>(A, R1, R0, nullptr, DT / 3.f, 1);
  mm256<<<dim3(16, 1), 256, 0, stream>>>(A, R0, R1, nullptr, DT / 2.f, 1);
  mm256<<<dim3(16, 1), 256, 0, stream>>>(A, R1, E + 65536, Wh + 65536, DT, 1);
  // Doubling levels: E[2^j + r] = E[2^j] * E[r], r = 1..cnt (fp16 Wh dual-written)
  for (int j = 0; j < 7; ++j) {
    int p   = 1 << j;
    int cnt = (TSTEPS - 1 - p < p) ? (TSTEPS - 1 - p) : p;
    mm256<<<dim3(16, cnt), 256, 0, stream>>>(E + (size_t)p * 65536, E + 65536,
                                             E + (size_t)(p + 1) * 65536,
                                             Wh + (size_t)(p + 1) * 65536, 1.f, 0);
  }

  // ---- convert X0 to fp16 ----
  f2h<<<1024, 256, 0, stream>>>(X0, Xh);

  // ---- Phase 2: big GEMM ----
  gemm_out<<<32 * 200, 256, 0, stream>>>(Xh, Wh, out);
}